// Round 1
// baseline (316.357 us; speedup 1.0000x reference)
//
#include <hip/hip_runtime.h>

typedef __bf16 bf16x8 __attribute__((ext_vector_type(8)));
typedef float f32x4 __attribute__((ext_vector_type(4)));
typedef unsigned short u16;

__device__ inline u16 f2bf(float f) {
  union { float f; unsigned int u; } v; v.f = f;
  unsigned int r = v.u + 0x7fffu + ((v.u >> 16) & 1u);
  return (u16)(r >> 16);
}

__device__ inline void load_lds16(const void* g, void* l) {
  __builtin_amdgcn_global_load_lds((const __attribute__((address_space(1))) unsigned int*)g,
                                   (__attribute__((address_space(3))) unsigned int*)l, 16, 0, 0);
}

__device__ inline float rmax16(float v) {
  v = fmaxf(v, __shfl_xor(v, 1, 16));
  v = fmaxf(v, __shfl_xor(v, 2, 16));
  v = fmaxf(v, __shfl_xor(v, 4, 16));
  v = fmaxf(v, __shfl_xor(v, 8, 16));
  return v;
}
__device__ inline float rsum16(float v) {
  v += __shfl_xor(v, 1, 16);
  v += __shfl_xor(v, 2, 16);
  v += __shfl_xor(v, 4, 16);
  v += __shfl_xor(v, 8, 16);
  return v;
}

// ---------------- prepass: fp32 -> bf16 ----------------
__global__ void cvt_bf16(const float* __restrict__ in, u16* __restrict__ out, int n) {
  int i = (blockIdx.x * blockDim.x + threadIdx.x) * 4;
  if (i < n) {
    float4 v = *(const float4*)(in + i);
    ushort4 o;
    o.x = f2bf(v.x); o.y = f2bf(v.y); o.z = f2bf(v.z); o.w = f2bf(v.w);
    *(ushort4*)(out + i) = o;
  }
}

// in [R][C] fp32 -> out [C][R] bf16
__global__ void transpose_cvt(const float* __restrict__ in, u16* __restrict__ out, int R, int C) {
  __shared__ float tile[32][33];
  int c0 = blockIdx.x * 32, r0 = blockIdx.y * 32;
  int tx = threadIdx.x;
#pragma unroll
  for (int i = threadIdx.y; i < 32; i += 8)
    tile[i][tx] = in[(size_t)(r0 + i) * C + c0 + tx];
  __syncthreads();
#pragma unroll
  for (int i = threadIdx.y; i < 32; i += 8)
    out[(size_t)(c0 + i) * R + r0 + tx] = f2bf(tile[tx][i]);
}

// ---------------- GEMM: C = A[M,K] * BT[N,K]^T + bias, bf16 in ----------------
template <int BF16_OUT>
__global__ __launch_bounds__(256) void gemm_bt(const u16* __restrict__ A, const u16* __restrict__ BT,
                                               const float* __restrict__ bias, void* __restrict__ Cv,
                                               int M, int N, int K) {
  __shared__ __align__(16) u16 As[128 * 32];
  __shared__ __align__(16) u16 Bs[128 * 32];
  const int tid = threadIdx.x;
  const int wave = tid >> 6, lane = tid & 63;
  const int g = lane >> 4, lr = lane & 15;
  const int m0 = blockIdx.y * 128, n0 = blockIdx.x * 128;
  const int wr = (wave >> 1) * 64, wc = (wave & 1) * 64;
  f32x4 acc[4][4] = {};

  for (int k0 = 0; k0 < K; k0 += 32) {
    __syncthreads();
#pragma unroll
    for (int j = 0; j < 2; ++j) {
      const int e = tid * 8 + j * 2048;
      const int r = e >> 5, c = e & 31;
      const u16* ga = A + (size_t)(m0 + r) * K + k0 + c;
      const u16* gb = BT + (size_t)(n0 + r) * K + k0 + c;
      load_lds16(ga, (void*)(As + wave * 512 + j * 2048));
      load_lds16(gb, (void*)(Bs + wave * 512 + j * 2048));
    }
    __syncthreads();
    const u16* pa = As + (wr + lr) * 32 + g * 8;
    const u16* pb = Bs + (wc + lr) * 32 + g * 8;
    bf16x8 a[4], b[4];
#pragma unroll
    for (int i = 0; i < 4; ++i) a[i] = *(const bf16x8*)(pa + i * 16 * 32);
#pragma unroll
    for (int j = 0; j < 4; ++j) b[j] = *(const bf16x8*)(pb + j * 16 * 32);
#pragma unroll
    for (int i = 0; i < 4; ++i)
#pragma unroll
      for (int j = 0; j < 4; ++j)
        acc[i][j] = __builtin_amdgcn_mfma_f32_16x16x32_bf16(a[i], b[j], acc[i][j], 0, 0, 0);
  }

#pragma unroll
  for (int i = 0; i < 4; ++i)
#pragma unroll
    for (int j = 0; j < 4; ++j)
#pragma unroll
      for (int r = 0; r < 4; ++r) {
        int row = m0 + wr + i * 16 + g * 4 + r;
        int col = n0 + wc + j * 16 + lr;
        float v = acc[i][j][r] + bias[col];
        if (BF16_OUT)
          ((u16*)Cv)[(size_t)row * N + col] = f2bf(v);
        else
          ((float*)Cv)[(size_t)row * N + col] = v;
      }
}

// ---------------- causal flash attention ----------------
// qkv: [4096][2304] bf16 (q | k | v), 12 heads x 64 dim. out a: [4096][768] bf16
__global__ __launch_bounds__(256) void attn(const u16* __restrict__ qkv, u16* __restrict__ aout) {
  const int h = blockIdx.y;
  const int qt = (int)gridDim.x - 1 - (int)blockIdx.x;  // heavy blocks first
  const int q0 = qt * 128;
  const int tid = threadIdx.x;
  const int wave = tid >> 6, lane = tid & 63;
  const int g = lane >> 4, lr = lane & 15;

  __shared__ __align__(16) u16 Ks[64 * 72];      // [key][dim] padded
  __shared__ __align__(16) u16 Vt[64 * 72];      // [dim][key] padded
  __shared__ __align__(16) u16 Ps[4][32 * 72];   // per-wave P tile [row][key] padded

  const int qrow_base = q0 + wave * 32;

  // Q fragments (A-layout): row = lr, k = dim
  bf16x8 qf[2][2];
#pragma unroll
  for (int rb = 0; rb < 2; ++rb)
#pragma unroll
    for (int kb = 0; kb < 2; ++kb) {
      const u16* p = qkv + (size_t)(qrow_base + rb * 16 + lr) * 2304 + h * 64 + kb * 32 + g * 8;
      qf[rb][kb] = *(const bf16x8*)p;
    }

  f32x4 O[2][4] = {};
  float mst[2][4], lst[2][4];
#pragma unroll
  for (int rb = 0; rb < 2; ++rb)
#pragma unroll
    for (int r = 0; r < 4; ++r) { mst[rb][r] = -__builtin_inff(); lst[rb][r] = 0.f; }

  const int nkt = (q0 + 128) >> 6;
  for (int t = 0; t < nkt; ++t) {
    const int kk0 = t * 64;
    __syncthreads();
    // stage K [64][64] and V^T
    {
      const int key = tid >> 2, d0 = (tid & 3) * 16;
      const u16* gk = qkv + (size_t)(kk0 + key) * 2304 + 768 + h * 64 + d0;
      uint4 k0v = *(const uint4*)gk;
      uint4 k1v = *(const uint4*)(gk + 8);
      *(uint4*)&Ks[key * 72 + d0] = k0v;
      *(uint4*)&Ks[key * 72 + d0 + 8] = k1v;
      const u16* gv = qkv + (size_t)(kk0 + key) * 2304 + 1536 + h * 64 + d0;
      u16 tmp[16];
      *(uint4*)tmp = *(const uint4*)gv;
      *(uint4*)(tmp + 8) = *(const uint4*)(gv + 8);
#pragma unroll
      for (int e = 0; e < 16; ++e) Vt[(d0 + e) * 72 + key] = tmp[e];
    }
    __syncthreads();

    // S = Q * K^T
    bf16x8 kf[4][2];
#pragma unroll
    for (int cb = 0; cb < 4; ++cb)
#pragma unroll
      for (int kb = 0; kb < 2; ++kb)
        kf[cb][kb] = *(const bf16x8*)&Ks[(cb * 16 + lr) * 72 + kb * 32 + g * 8];

    f32x4 s[2][4] = {};
#pragma unroll
    for (int rb = 0; rb < 2; ++rb)
#pragma unroll
      for (int cb = 0; cb < 4; ++cb)
#pragma unroll
        for (int kb = 0; kb < 2; ++kb)
          s[rb][cb] = __builtin_amdgcn_mfma_f32_16x16x32_bf16(qf[rb][kb], kf[cb][kb], s[rb][cb], 0, 0, 0);

    // online softmax (rows live in 16-lane groups; row = g*4+r within 16-block)
#pragma unroll
    for (int rb = 0; rb < 2; ++rb) {
#pragma unroll
      for (int r = 0; r < 4; ++r) {
        const int qrow = qrow_base + rb * 16 + g * 4 + r;
        float sv[4];
        float mx = -__builtin_inff();
#pragma unroll
        for (int cb = 0; cb < 4; ++cb) {
          const int kcol = kk0 + cb * 16 + lr;
          float v = s[rb][cb][r] * 0.125f;
          if (kcol > qrow) v = -__builtin_inff();
          sv[cb] = v;
          mx = fmaxf(mx, v);
        }
        mx = rmax16(mx);
        const float mo = mst[rb][r];
        const float mn = fmaxf(mo, mx);
        const float alpha = __expf(mo - mn);
        float rs = 0.f;
        float pv[4];
#pragma unroll
        for (int cb = 0; cb < 4; ++cb) { pv[cb] = __expf(sv[cb] - mn); rs += pv[cb]; }
        rs = rsum16(rs);
        lst[rb][r] = lst[rb][r] * alpha + rs;
        mst[rb][r] = mn;
#pragma unroll
        for (int cb = 0; cb < 4; ++cb) O[rb][cb][r] *= alpha;
#pragma unroll
        for (int cb = 0; cb < 4; ++cb)
          Ps[wave][(rb * 16 + g * 4 + r) * 72 + cb * 16 + lr] = f2bf(pv[cb]);
      }
    }
    asm volatile("s_waitcnt lgkmcnt(0)" ::: "memory");

    // O += P * V
    bf16x8 pa[2][2];
#pragma unroll
    for (int rb = 0; rb < 2; ++rb)
#pragma unroll
      for (int k2 = 0; k2 < 2; ++k2)
        pa[rb][k2] = *(const bf16x8*)&Ps[wave][(rb * 16 + lr) * 72 + k2 * 32 + g * 8];
    bf16x8 vb[4][2];
#pragma unroll
    for (int cb = 0; cb < 4; ++cb)
#pragma unroll
      for (int k2 = 0; k2 < 2; ++k2)
        vb[cb][k2] = *(const bf16x8*)&Vt[(cb * 16 + lr) * 72 + k2 * 32 + g * 8];
#pragma unroll
    for (int rb = 0; rb < 2; ++rb)
#pragma unroll
      for (int cb = 0; cb < 4; ++cb)
#pragma unroll
        for (int k2 = 0; k2 < 2; ++k2)
          O[rb][cb] = __builtin_amdgcn_mfma_f32_16x16x32_bf16(pa[rb][k2], vb[cb][k2], O[rb][cb], 0, 0, 0);
  }

  // epilogue: divide by l, store bf16
#pragma unroll
  for (int rb = 0; rb < 2; ++rb)
#pragma unroll
    for (int r = 0; r < 4; ++r) {
      const int row = qrow_base + rb * 16 + g * 4 + r;
      const float inv = 1.0f / lst[rb][r];
#pragma unroll
      for (int cb = 0; cb < 4; ++cb)
        aout[(size_t)row * 768 + h * 64 + cb * 16 + lr] = f2bf(O[rb][cb][r] * inv);
    }
}

// ---------------- launch ----------------
extern "C" void kernel_launch(void* const* d_in, const int* in_sizes, int n_in,
                              void* d_out, int out_size, void* d_ws, size_t ws_size,
                              hipStream_t stream) {
  const float* x = (const float*)d_in[0];
  const float* w_attn = (const float*)d_in[1];
  const float* b_attn = (const float*)d_in[2];
  const float* w_proj = (const float*)d_in[3];
  const float* b_proj = (const float*)d_in[4];
  float* out = (float*)d_out;

  const int S = 4096, D = 768;
  u16* xb = (u16*)d_ws;                 // [4096][768]
  u16* wTa = xb + (size_t)S * D;        // [2304][768]
  u16* wTp = wTa + (size_t)3 * D * D;   // [768][768]
  u16* qkv = wTp + (size_t)D * D;       // [4096][2304]
  u16* abuf = qkv + (size_t)S * 3 * D;  // [4096][768]

  cvt_bf16<<<(S * D) / 1024, 256, 0, stream>>>(x, xb, S * D);
  transpose_cvt<<<dim3((3 * D) / 32, D / 32), dim3(32, 8), 0, stream>>>(w_attn, wTa, D, 3 * D);
  transpose_cvt<<<dim3(D / 32, D / 32), dim3(32, 8), 0, stream>>>(w_proj, wTp, D, D);
  gemm_bt<1><<<dim3((3 * D) / 128, S / 128), 256, 0, stream>>>(xb, wTa, b_attn, qkv, S, 3 * D, D);
  attn<<<dim3(S / 128, 12), 256, 0, stream>>>(qkv, abuf);
  gemm_bt<0><<<dim3(D / 128, S / 128), 256, 0, stream>>>(abuf, wTp, b_proj, out, S, D, D);
}

// Round 2
// 284.080 us; speedup vs baseline: 1.1136x; 1.1136x over previous
//
#include <hip/hip_runtime.h>

typedef __bf16 bf16x8 __attribute__((ext_vector_type(8)));
typedef float f32x4 __attribute__((ext_vector_type(4)));
typedef unsigned short u16;

__device__ inline u16 f2bf(float f) {
  union { float f; unsigned int u; } v; v.f = f;
  unsigned int r = v.u + 0x7fffu + ((v.u >> 16) & 1u);
  return (u16)(r >> 16);
}

__device__ inline void load_lds16(const void* g, void* l) {
  __builtin_amdgcn_global_load_lds((const __attribute__((address_space(1))) unsigned int*)g,
                                   (__attribute__((address_space(3))) unsigned int*)l, 16, 0, 0);
}

__device__ inline float rmax16(float v) {
  v = fmaxf(v, __shfl_xor(v, 1, 16));
  v = fmaxf(v, __shfl_xor(v, 2, 16));
  v = fmaxf(v, __shfl_xor(v, 4, 16));
  v = fmaxf(v, __shfl_xor(v, 8, 16));
  return v;
}
__device__ inline float rsum16(float v) {
  v += __shfl_xor(v, 1, 16);
  v += __shfl_xor(v, 2, 16);
  v += __shfl_xor(v, 4, 16);
  v += __shfl_xor(v, 8, 16);
  return v;
}

// ---------------- prepass: fp32 -> bf16 ----------------
__global__ void cvt_bf16(const float* __restrict__ in, u16* __restrict__ out, int n) {
  int i = (blockIdx.x * blockDim.x + threadIdx.x) * 4;
  if (i < n) {
    float4 v = *(const float4*)(in + i);
    ushort4 o;
    o.x = f2bf(v.x); o.y = f2bf(v.y); o.z = f2bf(v.z); o.w = f2bf(v.w);
    *(ushort4*)(out + i) = o;
  }
}

// in [R][C] fp32 -> out [C][R] bf16
__global__ void transpose_cvt(const float* __restrict__ in, u16* __restrict__ out, int R, int C) {
  __shared__ float tile[32][33];
  int c0 = blockIdx.x * 32, r0 = blockIdx.y * 32;
  int tx = threadIdx.x;
#pragma unroll
  for (int i = threadIdx.y; i < 32; i += 8)
    tile[i][tx] = in[(size_t)(r0 + i) * C + c0 + tx];
  __syncthreads();
#pragma unroll
  for (int i = threadIdx.y; i < 32; i += 8)
    out[(size_t)(c0 + i) * R + r0 + tx] = f2bf(tile[tx][i]);
}

// ---------------- GEMM: C = A[M,K] * BT[N,K]^T + bias, bf16 in ----------------
template <int BF16_OUT>
__global__ __launch_bounds__(256) void gemm_bt(const u16* __restrict__ A, const u16* __restrict__ BT,
                                               const float* __restrict__ bias, void* __restrict__ Cv,
                                               int M, int N, int K) {
  __shared__ __align__(16) u16 As[128 * 32];
  __shared__ __align__(16) u16 Bs[128 * 32];
  const int tid = threadIdx.x;
  const int wave = tid >> 6, lane = tid & 63;
  const int g = lane >> 4, lr = lane & 15;
  const int m0 = blockIdx.y * 128, n0 = blockIdx.x * 128;
  const int wr = (wave >> 1) * 64, wc = (wave & 1) * 64;
  f32x4 acc[4][4] = {};

  for (int k0 = 0; k0 < K; k0 += 32) {
    __syncthreads();
#pragma unroll
    for (int j = 0; j < 2; ++j) {
      const int e = tid * 8 + j * 2048;
      const int r = e >> 5, c = e & 31;
      const u16* ga = A + (size_t)(m0 + r) * K + k0 + c;
      const u16* gb = BT + (size_t)(n0 + r) * K + k0 + c;
      load_lds16(ga, (void*)(As + wave * 512 + j * 2048));
      load_lds16(gb, (void*)(Bs + wave * 512 + j * 2048));
    }
    __syncthreads();
    const u16* pa = As + (wr + lr) * 32 + g * 8;
    const u16* pb = Bs + (wc + lr) * 32 + g * 8;
    bf16x8 a[4], b[4];
#pragma unroll
    for (int i = 0; i < 4; ++i) a[i] = *(const bf16x8*)(pa + i * 16 * 32);
#pragma unroll
    for (int j = 0; j < 4; ++j) b[j] = *(const bf16x8*)(pb + j * 16 * 32);
#pragma unroll
    for (int i = 0; i < 4; ++i)
#pragma unroll
      for (int j = 0; j < 4; ++j)
        acc[i][j] = __builtin_amdgcn_mfma_f32_16x16x32_bf16(a[i], b[j], acc[i][j], 0, 0, 0);
  }

#pragma unroll
  for (int i = 0; i < 4; ++i)
#pragma unroll
    for (int j = 0; j < 4; ++j)
#pragma unroll
      for (int r = 0; r < 4; ++r) {
        int row = m0 + wr + i * 16 + g * 4 + r;
        int col = n0 + wc + j * 16 + lr;
        float v = acc[i][j][r] + bias[col];
        if (BF16_OUT)
          ((u16*)Cv)[(size_t)row * N + col] = f2bf(v);
        else
          ((float*)Cv)[(size_t)row * N + col] = v;
      }
}

// ---------------- causal flash attention ----------------
// qkv: [4096][2304] bf16 (q | k | v), 12 heads x 64 dim. out a: [4096][768] bf16
// 512 threads = 8 waves; each wave owns 16 q-rows. Q-tile = 128 rows, KV-tile = 64.
__global__ __launch_bounds__(512, 4) void attn(const u16* __restrict__ qkv, u16* __restrict__ aout) {
  const int h = blockIdx.y;
  const int qt = (int)gridDim.x - 1 - (int)blockIdx.x;  // heavy blocks first
  const int q0 = qt * 128;
  const int tid = threadIdx.x;
  const int wave = tid >> 6, lane = tid & 63;
  const int g = lane >> 4, lr = lane & 15;

  __shared__ __align__(16) u16 Ks[64 * 72];      // [key][dim] padded
  __shared__ __align__(16) u16 Vt[64 * 72];      // [dim][key^swz] padded
  __shared__ __align__(16) u16 Ps[8][16 * 72];   // per-wave P tile [row][key] padded

  const int qrow_base = q0 + wave * 16;

  // Q fragments (A-layout): row = lr, k = dim
  bf16x8 qf[2];
#pragma unroll
  for (int kb = 0; kb < 2; ++kb) {
    const u16* p = qkv + (size_t)(qrow_base + lr) * 2304 + h * 64 + kb * 32 + g * 8;
    qf[kb] = *(const bf16x8*)p;
  }

  f32x4 O[4] = {};
  float mst[4], lst[4];
#pragma unroll
  for (int r = 0; r < 4; ++r) { mst[r] = -__builtin_inff(); lst[r] = 0.f; }

  const int nkt = (q0 + 128) >> 6;                  // tiles the block stages
  const int nkt_w = ((qrow_base + 15) >> 6) + 1;    // tiles this wave computes

  // staging map: one uint4 (8 dims) of one key per thread
  const int skey = tid >> 3;         // 0..63
  const int ssub = tid & 7;          // 0..7
  const int sd0 = ssub * 8;          // 0..56

  for (int t = 0; t < nkt; ++t) {
    const int kk0 = t * 64;
    __syncthreads();
    // stage K [key][dim] and V^T [dim][key ^ (sub<<3)]
    {
      const u16* gk = qkv + (size_t)(kk0 + skey) * 2304 + 768 + h * 64 + sd0;
      uint4 kv = *(const uint4*)gk;
      uint4 vv = *(const uint4*)(gk + 768);
      *(uint4*)&Ks[skey * 72 + sd0] = kv;
      u16 tmp[8];
      *(uint4*)tmp = vv;
      const int keyw = skey ^ (ssub << 3);
#pragma unroll
      for (int e = 0; e < 8; ++e) Vt[(sd0 + e) * 72 + keyw] = tmp[e];
    }
    __syncthreads();

    if (t < nkt_w) {
      // S = Q * K^T
      bf16x8 kf[4][2];
#pragma unroll
      for (int cb = 0; cb < 4; ++cb)
#pragma unroll
        for (int kb = 0; kb < 2; ++kb)
          kf[cb][kb] = *(const bf16x8*)&Ks[(cb * 16 + lr) * 72 + kb * 32 + g * 8];

      f32x4 s[4] = {};
#pragma unroll
      for (int cb = 0; cb < 4; ++cb)
#pragma unroll
        for (int kb = 0; kb < 2; ++kb)
          s[cb] = __builtin_amdgcn_mfma_f32_16x16x32_bf16(qf[kb], kf[cb][kb], s[cb], 0, 0, 0);

      const bool needmask = (kk0 + 63 > qrow_base);

      // online softmax: rows g*4+r live in lane group g across lr
#pragma unroll
      for (int r = 0; r < 4; ++r) {
        const int qrow = qrow_base + g * 4 + r;
        float sv[4];
        float mx = -__builtin_inff();
#pragma unroll
        for (int cb = 0; cb < 4; ++cb) {
          float v = s[cb][r] * 0.125f;
          if (needmask) {
            const int kcol = kk0 + cb * 16 + lr;
            if (kcol > qrow) v = -__builtin_inff();
          }
          sv[cb] = v;
        }
        mx = fmaxf(fmaxf(sv[0], sv[1]), fmaxf(sv[2], sv[3]));
        mx = rmax16(mx);
        const float mo = mst[r];
        const float mn = fmaxf(mo, mx);
        const float alpha = __expf(mo - mn);
        float rs = 0.f;
        float pv[4];
#pragma unroll
        for (int cb = 0; cb < 4; ++cb) { pv[cb] = __expf(sv[cb] - mn); rs += pv[cb]; }
        rs = rsum16(rs);
        lst[r] = lst[r] * alpha + rs;
        mst[r] = mn;
#pragma unroll
        for (int cb = 0; cb < 4; ++cb) O[cb][r] *= alpha;
#pragma unroll
        for (int cb = 0; cb < 4; ++cb)
          Ps[wave][(g * 4 + r) * 72 + cb * 16 + lr] = f2bf(pv[cb]);
      }
      asm volatile("s_waitcnt lgkmcnt(0)" ::: "memory");

      // O += P * V
      bf16x8 pa[2];
#pragma unroll
      for (int k2 = 0; k2 < 2; ++k2)
        pa[k2] = *(const bf16x8*)&Ps[wave][lr * 72 + k2 * 32 + g * 8];
      bf16x8 vb[4][2];
#pragma unroll
      for (int cb = 0; cb < 4; ++cb)
#pragma unroll
        for (int k2 = 0; k2 < 2; ++k2) {
          const int d = cb * 16 + lr;
          const int keyw = (k2 * 32 + g * 8) ^ (((d >> 3) & 7) << 3);
          vb[cb][k2] = *(const bf16x8*)&Vt[d * 72 + keyw];
        }
#pragma unroll
      for (int cb = 0; cb < 4; ++cb)
#pragma unroll
        for (int k2 = 0; k2 < 2; ++k2)
          O[cb] = __builtin_amdgcn_mfma_f32_16x16x32_bf16(pa[k2], vb[cb][k2], O[cb], 0, 0, 0);
    }
  }

  // epilogue: divide by l, store bf16
#pragma unroll
  for (int r = 0; r < 4; ++r) {
    const int row = qrow_base + g * 4 + r;
    const float inv = 1.0f / lst[r];
#pragma unroll
    for (int cb = 0; cb < 4; ++cb)
      aout[(size_t)row * 768 + h * 64 + cb * 16 + lr] = f2bf(O[cb][r] * inv);
  }
}

// ---------------- launch ----------------
extern "C" void kernel_launch(void* const* d_in, const int* in_sizes, int n_in,
                              void* d_out, int out_size, void* d_ws, size_t ws_size,
                              hipStream_t stream) {
  const float* x = (const float*)d_in[0];
  const float* w_attn = (const float*)d_in[1];
  const float* b_attn = (const float*)d_in[2];
  const float* w_proj = (const float*)d_in[3];
  const float* b_proj = (const float*)d_in[4];
  float* out = (float*)d_out;

  const int S = 4096, D = 768;
  u16* xb = (u16*)d_ws;                 // [4096][768]
  u16* wTa = xb + (size_t)S * D;        // [2304][768]
  u16* wTp = wTa + (size_t)3 * D * D;   // [768][768]
  u16* qkv = wTp + (size_t)D * D;       // [4096][2304]
  u16* abuf = qkv + (size_t)S * 3 * D;  // [4096][768]

  cvt_bf16<<<(S * D) / 1024, 256, 0, stream>>>(x, xb, S * D);
  transpose_cvt<<<dim3((3 * D) / 32, D / 32), dim3(32, 8), 0, stream>>>(w_attn, wTa, D, 3 * D);
  transpose_cvt<<<dim3(D / 32, D / 32), dim3(32, 8), 0, stream>>>(w_proj, wTp, D, D);
  gemm_bt<1><<<dim3((3 * D) / 128, S / 128), 256, 0, stream>>>(xb, wTa, b_attn, qkv, S, 3 * D, D);
  attn<<<dim3(S / 128, 12), 512, 0, stream>>>(qkv, abuf);
  gemm_bt<0><<<dim3(D / 128, S / 128), 256, 0, stream>>>(abuf, wTp, b_proj, out, S, D, D);
}